// Round 1
// baseline (2440.362 us; speedup 1.0000x reference)
//
#include <hip/hip_runtime.h>
#include <hip/hip_bf16.h>

typedef short bf16x8 __attribute__((ext_vector_type(8)));
typedef short s16x4 __attribute__((ext_vector_type(4)));
typedef float f32x4 __attribute__((ext_vector_type(4)));

static constexpr int MTOT = 16384;   // B*S
static constexpr int NDIM = 4096;    // D_out
static constexpr int KDIM = 4096;    // D_in
static constexpr float LORA_ALPHA = 16.0f;

// round-to-nearest-even f32 -> bf16 bits
__device__ __forceinline__ unsigned bf16rn_bits(float v) {
  unsigned b = __float_as_uint(v);
  return (b + 0x7FFFu + ((b >> 16) & 1u)) >> 16;
}

// split f32x4 into bf16 hi + bf16 lo (v ~= hi + lo, err ~2^-17 rel)
__device__ __forceinline__ void split4(const float4 v, s16x4& h, s16x4& l) {
  float f[4] = {v.x, v.y, v.z, v.w};
  #pragma unroll
  for (int e = 0; e < 4; ++e) {
    unsigned hb = bf16rn_bits(f[e]);
    float hf = __uint_as_float(hb << 16);
    float lv = f[e] - hf;
    h[e] = (short)hb;
    l[e] = (short)bf16rn_bits(lv);
  }
}

// ---------------- Kernel 1: T[m][r] = sum_k x[m][k] * A[r][k] ----------------
// 4 waves/block, each wave owns 4 m-rows (shares A reads across rows).
__global__ __launch_bounds__(256) void lora_T_kernel(
    const float* __restrict__ x, const float* __restrict__ A,
    float* __restrict__ T) {
  const int wave = threadIdx.x >> 6;
  const int lane = threadIdx.x & 63;
  const int m0 = blockIdx.x * 16 + wave * 4;

  float acc[4][16];
  #pragma unroll
  for (int i = 0; i < 4; ++i)
    #pragma unroll
    for (int r = 0; r < 16; ++r) acc[i][r] = 0.f;

  for (int k0 = 0; k0 < KDIM; k0 += 256) {
    const int k = k0 + lane * 4;
    float4 xv[4];
    #pragma unroll
    for (int i = 0; i < 4; ++i)
      xv[i] = *(const float4*)&x[(size_t)(m0 + i) * KDIM + k];
    #pragma unroll
    for (int r = 0; r < 16; ++r) {
      float4 av = *(const float4*)&A[r * KDIM + k];
      #pragma unroll
      for (int i = 0; i < 4; ++i) {
        acc[i][r] += xv[i].x * av.x + xv[i].y * av.y +
                     xv[i].z * av.z + xv[i].w * av.w;
      }
    }
  }

  // full 64-lane butterfly reduce for each of the 64 accumulators
  #pragma unroll
  for (int i = 0; i < 4; ++i)
    #pragma unroll
    for (int r = 0; r < 16; ++r) {
      float v = acc[i][r];
      #pragma unroll
      for (int off = 32; off; off >>= 1) v += __shfl_xor(v, off, 64);
      acc[i][r] = v;
    }

  const int i = lane >> 4, r = lane & 15;
  T[(size_t)(m0 + i) * 16 + r] = acc[i][r];  // 64 contiguous f32 per wave
}

// ---------------- Kernel 2: out = x@W^T (split-bf16 MFMA) + epilogue --------
// 128x128 tile, BK=64, 4 waves 2x2 each 64x64, 3-pass hi/lo MFMA.
__global__ __launch_bounds__(256, 2) void lora_gemm_kernel(
    const float* __restrict__ x, const float* __restrict__ W,
    const float* __restrict__ Bm, const float* __restrict__ bias,
    const float* __restrict__ T, float* __restrict__ out) {

  // planes: 0 = x_hi, 1 = x_lo, 2 = w_hi, 3 = w_lo ; each [128][64] bf16
  __shared__ short smem[4 * 128 * 64];  // 64 KB

  const int tid = threadIdx.x;
  // XCD-bijective swizzle (gridDim.x = 4096, divisible by 8)
  const int per = gridDim.x >> 3;
  const int swz = (blockIdx.x & 7) * per + (blockIdx.x >> 3);
  const int bm = swz / (NDIM / 128);
  const int bn = swz % (NDIM / 128);

  // staging map: 16 threads per row, 8 rows-chunks per thread
  const int srow = tid >> 4;      // 0..15
  const int sc4 = tid & 15;       // float4 column 0..15 (64 floats per row)
  const float* xg = x + (size_t)(bm * 128 + srow) * KDIM + sc4 * 4;
  const float* wg = W + (size_t)(bn * 128 + srow) * KDIM + sc4 * 4;

  float4 xr[8], wr[8];

  auto loadTile = [&](int kt) {
    const float* xp = xg + kt * 64;
    const float* wp = wg + kt * 64;
    #pragma unroll
    for (int i = 0; i < 8; ++i) {
      xr[i] = *(const float4*)(xp + (size_t)(i * 16) * KDIM);
      wr[i] = *(const float4*)(wp + (size_t)(i * 16) * KDIM);
    }
  };

  auto writeTile = [&]() {
    #pragma unroll
    for (int i = 0; i < 8; ++i) {
      const int row = srow + i * 16;
      // XOR swizzle on short index: bank-conflict-free b128 reads later
      const int idx = row * 64 + ((sc4 * 4) ^ ((row & 7) << 3));
      s16x4 h, l;
      split4(xr[i], h, l);
      *(s16x4*)&smem[idx] = h;
      *(s16x4*)&smem[8192 + idx] = l;
      split4(wr[i], h, l);
      *(s16x4*)&smem[16384 + idx] = h;
      *(s16x4*)&smem[24576 + idx] = l;
    }
  };

  const int lane = tid & 63;
  const int wave = tid >> 6;
  const int wm = wave >> 1, wn = wave & 1;
  const int frow = lane & 15;          // MFMA row/col-within-tile
  const int fk = (lane >> 4) * 8;      // k-offset within K=32 step

  f32x4 acc[4][4];
  #pragma unroll
  for (int i = 0; i < 4; ++i)
    #pragma unroll
    for (int j = 0; j < 4; ++j) acc[i][j] = (f32x4){0.f, 0.f, 0.f, 0.f};

  loadTile(0);
  constexpr int NT = KDIM / 64;
  for (int kt = 0; kt < NT; ++kt) {
    __syncthreads();               // previous compute done reading LDS
    writeTile();
    __syncthreads();               // tile staged
    if (kt + 1 < NT) loadTile(kt + 1);  // prefetch overlaps compute

    #pragma unroll
    for (int kk = 0; kk < 2; ++kk) {
      const int colk = kk * 32 + fk;
      bf16x8 ah[4], al[4], bh[4], bl[4];
      #pragma unroll
      for (int t = 0; t < 4; ++t) {
        const int ra = wm * 64 + t * 16 + frow;
        const int ia = ra * 64 + (colk ^ ((ra & 7) << 3));
        ah[t] = *(const bf16x8*)&smem[ia];
        al[t] = *(const bf16x8*)&smem[8192 + ia];
        const int rb = wn * 64 + t * 16 + frow;
        const int ib = rb * 64 + (colk ^ ((rb & 7) << 3));
        bh[t] = *(const bf16x8*)&smem[16384 + ib];
        bl[t] = *(const bf16x8*)&smem[24576 + ib];
      }
      #pragma unroll
      for (int mt = 0; mt < 4; ++mt)
        #pragma unroll
        for (int nt = 0; nt < 4; ++nt) {
          acc[mt][nt] = __builtin_amdgcn_mfma_f32_16x16x32_bf16(ah[mt], bh[nt], acc[mt][nt], 0, 0, 0);
          acc[mt][nt] = __builtin_amdgcn_mfma_f32_16x16x32_bf16(al[mt], bh[nt], acc[mt][nt], 0, 0, 0);
          acc[mt][nt] = __builtin_amdgcn_mfma_f32_16x16x32_bf16(ah[mt], bl[nt], acc[mt][nt], 0, 0, 0);
        }
    }
  }

  // ---- epilogue: + bias + ALPHA * (T @ B^T), all f32 ----
  const int m0 = bm * 128 + wm * 64;
  const int n0 = bn * 128 + wn * 64;

  float4 brow[4][4];
  float bs[4];
  #pragma unroll
  for (int nt = 0; nt < 4; ++nt) {
    const int n = n0 + nt * 16 + frow;
    #pragma unroll
    for (int q = 0; q < 4; ++q)
      brow[nt][q] = *(const float4*)&Bm[n * 16 + q * 4];
    bs[nt] = bias[n];
  }

  const int rbase = (lane >> 4) * 4;
  #pragma unroll
  for (int mt = 0; mt < 4; ++mt) {
    #pragma unroll
    for (int r = 0; r < 4; ++r) {
      const int m = m0 + mt * 16 + rbase + r;
      float4 t4[4];
      #pragma unroll
      for (int q = 0; q < 4; ++q)
        t4[q] = *(const float4*)&T[(size_t)m * 16 + q * 4];
      #pragma unroll
      for (int nt = 0; nt < 4; ++nt) {
        float corr =
            t4[0].x * brow[nt][0].x + t4[0].y * brow[nt][0].y + t4[0].z * brow[nt][0].z + t4[0].w * brow[nt][0].w +
            t4[1].x * brow[nt][1].x + t4[1].y * brow[nt][1].y + t4[1].z * brow[nt][1].z + t4[1].w * brow[nt][1].w +
            t4[2].x * brow[nt][2].x + t4[2].y * brow[nt][2].y + t4[2].z * brow[nt][2].z + t4[2].w * brow[nt][2].w +
            t4[3].x * brow[nt][3].x + t4[3].y * brow[nt][3].y + t4[3].z * brow[nt][3].z + t4[3].w * brow[nt][3].w;
        out[(size_t)m * NDIM + n0 + nt * 16 + frow] =
            acc[mt][nt][r] + bs[nt] + LORA_ALPHA * corr;
      }
    }
  }
}

extern "C" void kernel_launch(void* const* d_in, const int* in_sizes, int n_in,
                              void* d_out, int out_size, void* d_ws, size_t ws_size,
                              hipStream_t stream) {
  const float* x    = (const float*)d_in[0];
  const float* W    = (const float*)d_in[1];
  const float* A    = (const float*)d_in[2];
  const float* Bm   = (const float*)d_in[3];
  const float* bias = (const float*)d_in[4];
  float* out = (float*)d_out;
  float* T   = (float*)d_ws;   // 16384*16*4 = 1 MB scratch

  hipLaunchKernelGGL(lora_T_kernel, dim3(MTOT / 16), dim3(256), 0, stream,
                     x, A, T);
  hipLaunchKernelGGL(lora_gemm_kernel,
                     dim3((MTOT / 128) * (NDIM / 128)), dim3(256), 0, stream,
                     x, W, Bm, bias, T, out);
}

// Round 4
// 1998.314 us; speedup vs baseline: 1.2212x; 1.2212x over previous
//
#include <hip/hip_runtime.h>
#include <hip/hip_bf16.h>

typedef short bf16x8 __attribute__((ext_vector_type(8)));
typedef short s16x4 __attribute__((ext_vector_type(4)));
typedef float f32x4 __attribute__((ext_vector_type(4)));

static constexpr int MTOT = 16384;   // B*S
static constexpr int NDIM = 4096;    // D_out
static constexpr int KDIM = 4096;    // D_in
static constexpr int NKT  = KDIM / 64;          // K-tiles per row panel
static constexpr float LORA_ALPHA = 16.0f;

// ws layout (bytes)
static constexpr size_t OFF_AXH = 0;
static constexpr size_t OFF_AXL = OFF_AXH + (size_t)MTOT * KDIM * 2;
static constexpr size_t OFF_WH  = OFF_AXL + (size_t)MTOT * KDIM * 2;
static constexpr size_t OFF_WL  = OFF_WH  + (size_t)NDIM * KDIM * 2;
static constexpr size_t OFF_T   = OFF_WL  + (size_t)NDIM * KDIM * 2;
static constexpr size_t WS_NEED = OFF_T + (size_t)MTOT * 16 * 4;

// round-to-nearest-even f32 -> bf16 bits
__device__ __forceinline__ unsigned bf16rn_bits(float v) {
  unsigned b = __float_as_uint(v);
  return (b + 0x7FFFu + ((b >> 16) & 1u)) >> 16;
}

__device__ __forceinline__ void split4(const float4 v, s16x4& h, s16x4& l) {
  float f[4] = {v.x, v.y, v.z, v.w};
  #pragma unroll
  for (int e = 0; e < 4; ++e) {
    unsigned hb = bf16rn_bits(f[e]);
    float hf = __uint_as_float(hb << 16);
    float lv = f[e] - hf;
    h[e] = (short)hb;
    l[e] = (short)bf16rn_bits(lv);
  }
}

// async global->LDS, 16B per lane (literal size arg required)
typedef __attribute__((address_space(3))) unsigned int lds_u32;
typedef __attribute__((address_space(1))) const unsigned int glb_u32;
__device__ __forceinline__ void gl2lds16(const short* g, short* l) {
  __builtin_amdgcn_global_load_lds((glb_u32*)g, (lds_u32*)l, 16, 0, 0);
}

// ------------- Kernel 0: split f32 rows into tiled+swizzled bf16 hi/lo -------
// Tile blob layout: [rtile][ktile][128*64] shorts; within blob:
//   idx = row*64 + (kin ^ ((row&7)<<3))  (XOR swizzle on 8-short chunks)
__global__ __launch_bounds__(256) void convert_split_kernel(
    const float* __restrict__ src, short* __restrict__ dh,
    short* __restrict__ dl) {
  const size_t e = (size_t)blockIdx.x * 256 + threadIdx.x;  // 8-elem chunk id
  const int m  = (int)(e >> 9);         // row (4096/8 = 512 chunks per row)
  const int c8 = (int)(e & 511);
  const int k  = c8 << 3;
  const float* p = src + ((size_t)m << 12) + k;
  float4 v0 = *(const float4*)p;
  float4 v1 = *(const float4*)(p + 4);
  s16x4 h0, l0, h1, l1;
  split4(v0, h0, l0);
  split4(v1, h1, l1);
  const int rtile = m >> 7, row = m & 127, ktile = k >> 6, kin = k & 63;
  const size_t base = ((size_t)rtile * NKT + ktile) * 8192;
  const int idx = row * 64 + (kin ^ ((row & 7) << 3));
  bf16x8 h = {h0[0], h0[1], h0[2], h0[3], h1[0], h1[1], h1[2], h1[3]};
  bf16x8 l = {l0[0], l0[1], l0[2], l0[3], l1[0], l1[1], l1[2], l1[3]};
  *(bf16x8*)&dh[base + idx] = h;
  *(bf16x8*)&dl[base + idx] = l;
}

// ---------------- Kernel 1: T[m][r] = sum_k x[m][k] * A[r][k] ----------------
__global__ __launch_bounds__(256) void lora_T_kernel(
    const float* __restrict__ x, const float* __restrict__ A,
    float* __restrict__ T) {
  const int wave = threadIdx.x >> 6;
  const int lane = threadIdx.x & 63;
  const int m0 = blockIdx.x * 16 + wave * 4;

  float acc[4][16];
  #pragma unroll
  for (int i = 0; i < 4; ++i)
    #pragma unroll
    for (int r = 0; r < 16; ++r) acc[i][r] = 0.f;

  for (int k0 = 0; k0 < KDIM; k0 += 256) {
    const int k = k0 + lane * 4;
    float4 xv[4];
    #pragma unroll
    for (int i = 0; i < 4; ++i)
      xv[i] = *(const float4*)&x[(size_t)(m0 + i) * KDIM + k];
    #pragma unroll
    for (int r = 0; r < 16; ++r) {
      float4 av = *(const float4*)&A[r * KDIM + k];
      #pragma unroll
      for (int i = 0; i < 4; ++i) {
        acc[i][r] += xv[i].x * av.x + xv[i].y * av.y +
                     xv[i].z * av.z + xv[i].w * av.w;
      }
    }
  }

  #pragma unroll
  for (int i = 0; i < 4; ++i)
    #pragma unroll
    for (int r = 0; r < 16; ++r) {
      float v = acc[i][r];
      #pragma unroll
      for (int off = 32; off; off >>= 1) v += __shfl_xor(v, off, 64);
      acc[i][r] = v;
    }

  const int i = lane >> 4, r = lane & 15;
  T[(size_t)(m0 + i) * 16 + r] = acc[i][r];
}

// -------- Kernel 2: out = x@W^T via pre-split bf16 planes (3-pass MFMA) -----
// 128x128 tile, BK=64, 8 waves (2x4), global_load_lds staging, single buffer.
__global__ __launch_bounds__(512, 4) void lora_gemm_pre(
    const short* __restrict__ Axh, const short* __restrict__ Axl,
    const short* __restrict__ Wh,  const short* __restrict__ Wl,
    const float* __restrict__ Bm,  const float* __restrict__ bias,
    const float* __restrict__ T,   float* __restrict__ out) {

  __shared__ short smem[4 * 128 * 64];  // xh | xl | wh | wl, 64 KB
  short* const sxh = smem;
  short* const sxl = smem + 8192;
  short* const swh = smem + 16384;
  short* const swl = smem + 24576;

  const int tid = threadIdx.x;
  // XCD-bijective swizzle (gridDim.x = 4096, divisible by 8)
  const int per = gridDim.x >> 3;
  const int swz = (blockIdx.x & 7) * per + (blockIdx.x >> 3);
  const int bm = swz / (NDIM / 128);
  const int bn = swz % (NDIM / 128);

  const short* baseAh = Axh + ((size_t)bm * NKT) * 8192;
  const short* baseAl = Axl + ((size_t)bm * NKT) * 8192;
  const short* baseWh = Wh + ((size_t)bn * NKT) * 8192;
  const short* baseWl = Wl + ((size_t)bn * NKT) * 8192;

  const int lane = tid & 63;
  const int wave = tid >> 6;
  const int wm = wave >> 2, wn = wave & 3;   // 2 x 4 wave grid
  const int frow = lane & 15;
  const int fk = (lane >> 4) * 8;

  f32x4 acc[4][2];
  #pragma unroll
  for (int i = 0; i < 4; ++i)
    #pragma unroll
    for (int j = 0; j < 2; ++j) acc[i][j] = (f32x4){0.f, 0.f, 0.f, 0.f};

  const int soff0 = tid * 8;          // shorts; threads cover 512*16B = 8 KB
  const int soff1 = soff0 + 4096;     // second 8 KB half of each 16 KB plane

  for (int kt = 0; kt < NKT; ++kt) {
    __syncthreads();   // previous tile's compute done before overwrite
    {
      const size_t tb = (size_t)kt * 8192;
      gl2lds16(baseAh + tb + soff0, sxh + soff0);
      gl2lds16(baseAh + tb + soff1, sxh + soff1);
      gl2lds16(baseAl + tb + soff0, sxl + soff0);
      gl2lds16(baseAl + tb + soff1, sxl + soff1);
      gl2lds16(baseWh + tb + soff0, swh + soff0);
      gl2lds16(baseWh + tb + soff1, swh + soff1);
      gl2lds16(baseWl + tb + soff0, swl + soff0);
      gl2lds16(baseWl + tb + soff1, swl + soff1);
    }
    __syncthreads();   // compiler drains vmcnt(0) before this barrier

    #pragma unroll
    for (int kk = 0; kk < 2; ++kk) {
      const int colk = kk * 32 + fk;
      bf16x8 ah[4], al[4], bh[2], bl[2];
      #pragma unroll
      for (int mt = 0; mt < 4; ++mt) {
        const int ra = wm * 64 + mt * 16 + frow;
        const int ia = ra * 64 + (colk ^ ((ra & 7) << 3));
        ah[mt] = *(const bf16x8*)&sxh[ia];
        al[mt] = *(const bf16x8*)&sxl[ia];
      }
      #pragma unroll
      for (int nt = 0; nt < 2; ++nt) {
        const int rb = wn * 32 + nt * 16 + frow;
        const int ib = rb * 64 + (colk ^ ((rb & 7) << 3));
        bh[nt] = *(const bf16x8*)&swh[ib];
        bl[nt] = *(const bf16x8*)&swl[ib];
      }
      // 3 passes, pass-outer order to avoid back-to-back same-acc chains
      #pragma unroll
      for (int mt = 0; mt < 4; ++mt)
        #pragma unroll
        for (int nt = 0; nt < 2; ++nt)
          acc[mt][nt] = __builtin_amdgcn_mfma_f32_16x16x32_bf16(ah[mt], bh[nt], acc[mt][nt], 0, 0, 0);
      #pragma unroll
      for (int mt = 0; mt < 4; ++mt)
        #pragma unroll
        for (int nt = 0; nt < 2; ++nt)
          acc[mt][nt] = __builtin_amdgcn_mfma_f32_16x16x32_bf16(al[mt], bh[nt], acc[mt][nt], 0, 0, 0);
      #pragma unroll
      for (int mt = 0; mt < 4; ++mt)
        #pragma unroll
        for (int nt = 0; nt < 2; ++nt)
          acc[mt][nt] = __builtin_amdgcn_mfma_f32_16x16x32_bf16(ah[mt], bl[nt], acc[mt][nt], 0, 0, 0);
    }
  }

  // ---- epilogue: + bias + ALPHA * (T @ B^T), all f32 ----
  const int m0 = bm * 128 + wm * 64;
  const int n0 = bn * 128 + wn * 32;

  float4 brow[2][4];
  float bs[2];
  #pragma unroll
  for (int nt = 0; nt < 2; ++nt) {
    const int n = n0 + nt * 16 + frow;
    #pragma unroll
    for (int q = 0; q < 4; ++q)
      brow[nt][q] = *(const float4*)&Bm[n * 16 + q * 4];
    bs[nt] = bias[n];
  }

  const int rbase = (lane >> 4) * 4;
  #pragma unroll
  for (int mt = 0; mt < 4; ++mt) {
    #pragma unroll
    for (int r = 0; r < 4; ++r) {
      const int m = m0 + mt * 16 + rbase + r;
      float4 t4[4];
      #pragma unroll
      for (int q = 0; q < 4; ++q)
        t4[q] = *(const float4*)&T[(size_t)m * 16 + q * 4];
      #pragma unroll
      for (int nt = 0; nt < 2; ++nt) {
        float corr =
            t4[0].x * brow[nt][0].x + t4[0].y * brow[nt][0].y + t4[0].z * brow[nt][0].z + t4[0].w * brow[nt][0].w +
            t4[1].x * brow[nt][1].x + t4[1].y * brow[nt][1].y + t4[1].z * brow[nt][1].z + t4[1].w * brow[nt][1].w +
            t4[2].x * brow[nt][2].x + t4[2].y * brow[nt][2].y + t4[2].z * brow[nt][2].z + t4[2].w * brow[nt][2].w +
            t4[3].x * brow[nt][3].x + t4[3].y * brow[nt][3].y + t4[3].z * brow[nt][3].z + t4[3].w * brow[nt][3].w;
        out[(size_t)m * NDIM + n0 + nt * 16 + frow] =
            acc[mt][nt][r] + bs[nt] + LORA_ALPHA * corr;
      }
    }
  }
}

// ---------------- Fallback (round-1 kernel): reg-staged split GEMM ----------
__global__ __launch_bounds__(256, 2) void lora_gemm_fallback(
    const float* __restrict__ x, const float* __restrict__ W,
    const float* __restrict__ Bm, const float* __restrict__ bias,
    const float* __restrict__ T, float* __restrict__ out) {

  __shared__ short smem[4 * 128 * 64];

  const int tid = threadIdx.x;
  const int per = gridDim.x >> 3;
  const int swz = (blockIdx.x & 7) * per + (blockIdx.x >> 3);
  const int bm = swz / (NDIM / 128);
  const int bn = swz % (NDIM / 128);

  const int srow = tid >> 4;
  const int sc4 = tid & 15;
  const float* xg = x + (size_t)(bm * 128 + srow) * KDIM + sc4 * 4;
  const float* wg = W + (size_t)(bn * 128 + srow) * KDIM + sc4 * 4;

  float4 xr[8], wr[8];

  auto loadTile = [&](int kt) {
    const float* xp = xg + kt * 64;
    const float* wp = wg + kt * 64;
    #pragma unroll
    for (int i = 0; i < 8; ++i) {
      xr[i] = *(const float4*)(xp + (size_t)(i * 16) * KDIM);
      wr[i] = *(const float4*)(wp + (size_t)(i * 16) * KDIM);
    }
  };

  auto writeTile = [&]() {
    #pragma unroll
    for (int i = 0; i < 8; ++i) {
      const int row = srow + i * 16;
      const int idx = row * 64 + ((sc4 * 4) ^ ((row & 7) << 3));
      s16x4 h, l;
      split4(xr[i], h, l);
      *(s16x4*)&smem[idx] = h;
      *(s16x4*)&smem[8192 + idx] = l;
      split4(wr[i], h, l);
      *(s16x4*)&smem[16384 + idx] = h;
      *(s16x4*)&smem[24576 + idx] = l;
    }
  };

  const int lane = tid & 63;
  const int wave = tid >> 6;
  const int wm = wave >> 1, wn = wave & 1;
  const int frow = lane & 15;
  const int fk = (lane >> 4) * 8;

  f32x4 acc[4][4];
  #pragma unroll
  for (int i = 0; i < 4; ++i)
    #pragma unroll
    for (int j = 0; j < 4; ++j) acc[i][j] = (f32x4){0.f, 0.f, 0.f, 0.f};

  loadTile(0);
  constexpr int NT = KDIM / 64;
  for (int kt = 0; kt < NT; ++kt) {
    __syncthreads();
    writeTile();
    __syncthreads();
    if (kt + 1 < NT) loadTile(kt + 1);

    #pragma unroll
    for (int kk = 0; kk < 2; ++kk) {
      const int colk = kk * 32 + fk;
      bf16x8 ah[4], al[4], bh[4], bl[4];
      #pragma unroll
      for (int t = 0; t < 4; ++t) {
        const int ra = wm * 64 + t * 16 + frow;
        const int ia = ra * 64 + (colk ^ ((ra & 7) << 3));
        ah[t] = *(const bf16x8*)&smem[ia];
        al[t] = *(const bf16x8*)&smem[8192 + ia];
        const int rb = wn * 64 + t * 16 + frow;
        const int ib = rb * 64 + (colk ^ ((rb & 7) << 3));
        bh[t] = *(const bf16x8*)&smem[16384 + ib];
        bl[t] = *(const bf16x8*)&smem[24576 + ib];
      }
      #pragma unroll
      for (int mt = 0; mt < 4; ++mt)
        #pragma unroll
        for (int nt = 0; nt < 4; ++nt) {
          acc[mt][nt] = __builtin_amdgcn_mfma_f32_16x16x32_bf16(ah[mt], bh[nt], acc[mt][nt], 0, 0, 0);
          acc[mt][nt] = __builtin_amdgcn_mfma_f32_16x16x32_bf16(al[mt], bh[nt], acc[mt][nt], 0, 0, 0);
          acc[mt][nt] = __builtin_amdgcn_mfma_f32_16x16x32_bf16(ah[mt], bl[nt], acc[mt][nt], 0, 0, 0);
        }
    }
  }

  const int m0 = bm * 128 + wm * 64;
  const int n0 = bn * 128 + wn * 64;

  float4 brow[4][4];
  float bs[4];
  #pragma unroll
  for (int nt = 0; nt < 4; ++nt) {
    const int n = n0 + nt * 16 + frow;
    #pragma unroll
    for (int q = 0; q < 4; ++q)
      brow[nt][q] = *(const float4*)&Bm[n * 16 + q * 4];
    bs[nt] = bias[n];
  }

  const int rbase = (lane >> 4) * 4;
  #pragma unroll
  for (int mt = 0; mt < 4; ++mt) {
    #pragma unroll
    for (int r = 0; r < 4; ++r) {
      const int m = m0 + mt * 16 + rbase + r;
      float4 t4[4];
      #pragma unroll
      for (int q = 0; q < 4; ++q)
        t4[q] = *(const float4*)&T[(size_t)m * 16 + q * 4];
      #pragma unroll
      for (int nt = 0; nt < 4; ++nt) {
        float corr =
            t4[0].x * brow[nt][0].x + t4[0].y * brow[nt][0].y + t4[0].z * brow[nt][0].z + t4[0].w * brow[nt][0].w +
            t4[1].x * brow[nt][1].x + t4[1].y * brow[nt][1].y + t4[1].z * brow[nt][1].z + t4[1].w * brow[nt][1].w +
            t4[2].x * brow[nt][2].x + t4[2].y * brow[nt][2].y + t4[2].z * brow[nt][2].z + t4[2].w * brow[nt][2].w +
            t4[3].x * brow[nt][3].x + t4[3].y * brow[nt][3].y + t4[3].z * brow[nt][3].z + t4[3].w * brow[nt][3].w;
        out[(size_t)m * NDIM + n0 + nt * 16 + frow] =
            acc[mt][nt][r] + bs[nt] + LORA_ALPHA * corr;
      }
    }
  }
}

extern "C" void kernel_launch(void* const* d_in, const int* in_sizes, int n_in,
                              void* d_out, int out_size, void* d_ws, size_t ws_size,
                              hipStream_t stream) {
  const float* x    = (const float*)d_in[0];
  const float* W    = (const float*)d_in[1];
  const float* A    = (const float*)d_in[2];
  const float* Bm   = (const float*)d_in[3];
  const float* bias = (const float*)d_in[4];
  float* out = (float*)d_out;
  char* ws = (char*)d_ws;

  if (ws_size >= WS_NEED) {
    short* Axh = (short*)(ws + OFF_AXH);
    short* Axl = (short*)(ws + OFF_AXL);
    short* Wh  = (short*)(ws + OFF_WH);
    short* Wl  = (short*)(ws + OFF_WL);
    float* T   = (float*)(ws + OFF_T);

    hipLaunchKernelGGL(convert_split_kernel, dim3(NDIM * 2), dim3(256), 0,
                       stream, W, Wh, Wl);
    hipLaunchKernelGGL(convert_split_kernel, dim3(MTOT * 2), dim3(256), 0,
                       stream, x, Axh, Axl);
    hipLaunchKernelGGL(lora_T_kernel, dim3(MTOT / 16), dim3(256), 0, stream,
                       x, A, T);
    hipLaunchKernelGGL(lora_gemm_pre,
                       dim3((MTOT / 128) * (NDIM / 128)), dim3(512), 0, stream,
                       Axh, Axl, Wh, Wl, Bm, bias, T, out);
  } else {
    float* T = (float*)ws;  // 1 MB
    hipLaunchKernelGGL(lora_T_kernel, dim3(MTOT / 16), dim3(256), 0, stream,
                       x, A, T);
    hipLaunchKernelGGL(lora_gemm_fallback,
                       dim3((MTOT / 128) * (NDIM / 128)), dim3(256), 0, stream,
                       x, W, Bm, bias, T, out);
  }
}